// Round 5
// baseline (551.512 us; speedup 1.0000x reference)
//
#include <hip/hip_runtime.h>
#include <hip/hip_fp16.h>
#include <math.h>

#define Bq 4
#define Nq 512
#define Dq 4
#define Hq 256

typedef _Float16 f16x8 __attribute__((ext_vector_type(8)));
typedef float f32x4 __attribute__((ext_vector_type(4)));

// packed fp16 add + relu on 8 halves (v_pk_add_f16 + v_pk_max_f16)
__device__ __forceinline__ f16x8 hadd_relu(f16x8 u, f16x8 v) {
    f16x8 s = u + v;
    const f16x8 z = (f16x8)(_Float16)0.0f;
    return __builtin_elementwise_max(s, z);
}

// ---------------- kernel 1: U/V precompute (separable first edge layer) ----
// U[b,n,k] = b_e1[k] + x[b,n,:] @ W_e1[0:4,k]   (innode half, j side)
// V[b,n,k] =          x[b,n,:] @ W_e1[4:8,k]    (outnode half, i side)
__global__ __launch_bounds__(256) void prep_uv(
    const float* __restrict__ x, const float* __restrict__ We1,
    const float* __restrict__ be1, __half* __restrict__ U, __half* __restrict__ V) {
    const int bn = blockIdx.x;   // 0..B*N-1
    const int k = threadIdx.x;   // 0..255
    const float* xp = x + bn * Dq;
    const float x0 = xp[0], x1 = xp[1], x2 = xp[2], x3 = xp[3];
    float u = be1[k];
    u = fmaf(x0, We1[0 * 256 + k], u);
    u = fmaf(x1, We1[1 * 256 + k], u);
    u = fmaf(x2, We1[2 * 256 + k], u);
    u = fmaf(x3, We1[3 * 256 + k], u);
    float v = x0 * We1[4 * 256 + k];
    v = fmaf(x1, We1[5 * 256 + k], v);
    v = fmaf(x2, We1[6 * 256 + k], v);
    v = fmaf(x3, We1[7 * 256 + k], v);
    U[(size_t)bn * Hq + k] = __float2half(u);
    V[(size_t)bn * Hq + k] = __float2half(v);
}

// ---------------- kernel 2: fused edge GEMM + adjacency aggregation --------
// agg[b,j,h] = sum_i adj[b,i,j] * relu( relu(U[b,j,:]+V[b,i,:]) @ We2[:,h] + be2[h] )
// grid 512 = b(4) x jtile(32, 16 j each) x hquarter(4, 64 h each)
// R4 post-mortem: structure was barrier-bound, not LDS-bound. This version has
// ZERO in-loop barriers: V and adj are read straight from global into regs
// (quad-broadcast addresses, L2-resident, VMEM pipe), U fragment hoisted to
// 16 VGPRs from global, B (We2^T) read from LDS (only in-loop LDS traffic).
// 1-ks register lookahead on V loads pipelines VMEM latency under compute.
// Epilogue: LDS 4-wave reduce in red (aliases dead Wt) + plain stores.
__global__ __launch_bounds__(256, 2) void edge_gemm(
    const __half* __restrict__ U, const __half* __restrict__ V,
    const float* __restrict__ We2, const float* __restrict__ be2,
    const float* __restrict__ adj, float* __restrict__ aggws) {
    __shared__ __align__(16) char smem[32768];   // Wt 32KB; red 16KB aliases after loop
    __half* Wt = (__half*)smem;
    float* red = (float*)smem;

    const int bid = blockIdx.x;
    const int hq_ = bid & 3;
    const int jt = (bid >> 2) & 31;
    const int b = bid >> 7;
    const int h_base = hq_ * 64;
    const int j_base = jt * 16;
    const int t = threadIdx.x;
    const int lane = t & 63;
    const int w = t >> 6;       // wave 0..3
    const int q = lane >> 4;    // quad 0..3
    const int l15 = lane & 15;

    // ---- stage Wt (once): transpose + fp16-convert We2 quarter ----
    // Wt[n][k] = We2[k][h_base+n], XOR-swizzled 16B chunks
    {
        const int n = t & 63;
        const int swz = n & 31;
        for (int kk = (t >> 6); kk < 256; kk += 4) {
            float val = We2[kk * 256 + h_base + n];
            Wt[n * 256 + ((((kk >> 3) ^ swz)) << 3) + (kk & 7)] = __float2half(val);
        }
    }

    // ---- hoist U fragment (ch-invariant) straight from global ----
    // A row m = l15 -> j_local = l15; chunk c = ks*4+q
    f16x8 uvec[8];
#pragma unroll
    for (int ks = 0; ks < 8; ++ks) {
        const int c = ks * 4 + q;
        uvec[ks] = *(const f16x8*)&U[(size_t)(b * Nq + j_base + l15) * Hq + c * 8];
    }

    float bias[4];
#pragma unroll
    for (int nt = 0; nt < 4; ++nt) bias[nt] = be2[h_base + nt * 16 + l15];

    f32x4 agg[4];
#pragma unroll
    for (int nt = 0; nt < 4; ++nt) agg[nt] = (f32x4){0.f, 0.f, 0.f, 0.f};

    __syncthreads();  // Wt ready; no more barriers until after the main loop

    const __half* Vb = V + (size_t)b * Nq * Hq;
    const float* adjb = adj + (size_t)b * Nq * Nq;

    for (int ch = 0; ch < 32; ++ch) {
        const int i0 = ch * 16 + w * 4;   // this wave's 4 i rows (global i index)

        // adj rows for the epilogue: av[mi][r] = adj[i0+mi][j_base+q*4+r]
        f32x4 av[4];
#pragma unroll
        for (int mi = 0; mi < 4; ++mi)
            av[mi] = *(const f32x4*)&adjb[(size_t)(i0 + mi) * Nq + j_base + q * 4];

        // acc init to be2 bias (bias applied pre-relu)
        f32x4 acc[4][4];
#pragma unroll
        for (int mi = 0; mi < 4; ++mi)
#pragma unroll
            for (int nt = 0; nt < 4; ++nt)
                acc[mi][nt] = (f32x4){bias[nt], bias[nt], bias[nt], bias[nt]};

        // V fragments: vcur for ks, vnxt prefetched for ks+1 (reg lookahead)
        f16x8 vcur[4], vnxt[4];
#pragma unroll
        for (int mi = 0; mi < 4; ++mi)
            vcur[mi] = *(const f16x8*)&Vb[(size_t)(i0 + mi) * Hq + q * 8];  // c=q at ks=0

#pragma unroll
        for (int ks = 0; ks < 8; ++ks) {
            if (ks < 7) {
                const int cn = (ks + 1) * 4 + q;
#pragma unroll
                for (int mi = 0; mi < 4; ++mi)
                    vnxt[mi] = *(const f16x8*)&Vb[(size_t)(i0 + mi) * Hq + cn * 8];
            }
            const int c = ks * 4 + q;
            f16x8 afrag[4];
#pragma unroll
            for (int mi = 0; mi < 4; ++mi)
                afrag[mi] = hadd_relu(uvec[ks], vcur[mi]);
            f16x8 bf[4];
#pragma unroll
            for (int nt = 0; nt < 4; ++nt) {
                const int rn = nt * 16 + l15;
                bf[nt] = *(const f16x8*)&Wt[rn * 256 + ((c ^ (rn & 31)) << 3)];
            }
#pragma unroll
            for (int mi = 0; mi < 4; ++mi)
#pragma unroll
                for (int nt = 0; nt < 4; ++nt)
                    acc[mi][nt] = __builtin_amdgcn_mfma_f32_16x16x32_f16(
                        afrag[mi], bf[nt], acc[mi][nt], 0, 0, 0);
#pragma unroll
            for (int mi = 0; mi < 4; ++mi) vcur[mi] = vnxt[mi];
        }

        // epilogue: agg[j,h] += adj[i,j] * relu(z)   (C/D row = q*4+r -> j_local)
#pragma unroll
        for (int mi = 0; mi < 4; ++mi) {
#pragma unroll
            for (int nt = 0; nt < 4; ++nt) {
                agg[nt][0] = fmaf(av[mi][0], fmaxf(acc[mi][nt][0], 0.f), agg[nt][0]);
                agg[nt][1] = fmaf(av[mi][1], fmaxf(acc[mi][nt][1], 0.f), agg[nt][1]);
                agg[nt][2] = fmaf(av[mi][2], fmaxf(acc[mi][nt][2], 0.f), agg[nt][2]);
                agg[nt][3] = fmaf(av[mi][3], fmaxf(acc[mi][nt][3], 0.f), agg[nt][3]);
            }
        }
    }

    // ---- cross-wave i-reduction in LDS (red aliases dead Wt), plain store --
    __syncthreads();  // all waves past their last Wt read
#pragma unroll
    for (int nt = 0; nt < 4; ++nt)
#pragma unroll
        for (int r = 0; r < 4; ++r)
            red[w * 1024 + (q * 4 + r) * 64 + nt * 16 + l15] = agg[nt][r];
    __syncthreads();
    {
        const int j = t >> 4;
        const int h0 = (t & 15) * 4;
        f32x4 s = *(const f32x4*)&red[0 * 1024 + j * 64 + h0];
        s += *(const f32x4*)&red[1 * 1024 + j * 64 + h0];
        s += *(const f32x4*)&red[2 * 1024 + j * 64 + h0];
        s += *(const f32x4*)&red[3 * 1024 + j * 64 + h0];
        *(f32x4*)&aggws[(size_t)(b * Nq + j_base + j) * Hq + h_base + h0] = s;
    }
}

// ---------------- kernel 3: node MLP tail + log_softmax -------------------
// 4 nodes per block; activations packed float4-per-k across nodes.
__global__ __launch_bounds__(256) void tail_kernel(
    const float* __restrict__ aggws, const float* __restrict__ x,
    const float* __restrict__ Wn1, const float* __restrict__ bn1,
    const float* __restrict__ Wn2, const float* __restrict__ bn2,
    const float* __restrict__ Wo1, const float* __restrict__ bo1,
    const float* __restrict__ Wo, const float* __restrict__ bo,
    float* __restrict__ out) {
    __shared__ __align__(16) float bufA[256 * 4];
    __shared__ __align__(16) float bufB[256 * 4];
    __shared__ float xs[4][4];
    __shared__ float s5[4][4];
    const int bid = blockIdx.x;
    const int b = bid >> 7;
    const int n0 = (bid & 127) * 4;
    const int t = threadIdx.x;

#pragma unroll
    for (int ni = 0; ni < 4; ++ni)
        bufA[t * 4 + ni] = aggws[(size_t)(b * Nq + n0 + ni) * Hq + t];
    if (t < 16) xs[t >> 2][t & 3] = x[(size_t)(b * Nq + n0 + (t >> 2)) * Dq + (t & 3)];
    __syncthreads();

    float c0, c1, c2, c3;
    // layer n1: relu(agg @ Wn1 + bn1)
    c0 = c1 = c2 = c3 = bn1[t];
#pragma unroll 8
    for (int k = 0; k < 256; ++k) {
        const float wv = Wn1[k * 256 + t];
        const float4 av = *(const float4*)&bufA[k * 4];
        c0 = fmaf(av.x, wv, c0); c1 = fmaf(av.y, wv, c1);
        c2 = fmaf(av.z, wv, c2); c3 = fmaf(av.w, wv, c3);
    }
    bufB[t * 4 + 0] = fmaxf(c0, 0.f); bufB[t * 4 + 1] = fmaxf(c1, 0.f);
    bufB[t * 4 + 2] = fmaxf(c2, 0.f); bufB[t * 4 + 3] = fmaxf(c3, 0.f);
    __syncthreads();

    // layer n2: relu(out1 @ Wn2 + bn2)
    c0 = c1 = c2 = c3 = bn2[t];
#pragma unroll 8
    for (int k = 0; k < 256; ++k) {
        const float wv = Wn2[k * 256 + t];
        const float4 av = *(const float4*)&bufB[k * 4];
        c0 = fmaf(av.x, wv, c0); c1 = fmaf(av.y, wv, c1);
        c2 = fmaf(av.z, wv, c2); c3 = fmaf(av.w, wv, c3);
    }
    bufA[t * 4 + 0] = fmaxf(c0, 0.f); bufA[t * 4 + 1] = fmaxf(c1, 0.f);
    bufA[t * 4 + 2] = fmaxf(c2, 0.f); bufA[t * 4 + 3] = fmaxf(c3, 0.f);
    __syncthreads();

    // layer o1: concat(x, out2) @ Wo1 + bo1   (no relu)
    c0 = c1 = c2 = c3 = bo1[t];
#pragma unroll
    for (int d = 0; d < 4; ++d) {
        const float wv = Wo1[d * 256 + t];
        c0 = fmaf(xs[0][d], wv, c0); c1 = fmaf(xs[1][d], wv, c1);
        c2 = fmaf(xs[2][d], wv, c2); c3 = fmaf(xs[3][d], wv, c3);
    }
#pragma unroll 8
    for (int k = 0; k < 256; ++k) {
        const float wv = Wo1[(4 + k) * 256 + t];
        const float4 av = *(const float4*)&bufA[k * 4];
        c0 = fmaf(av.x, wv, c0); c1 = fmaf(av.y, wv, c1);
        c2 = fmaf(av.z, wv, c2); c3 = fmaf(av.w, wv, c3);
    }
    bufB[t * 4 + 0] = c0; bufB[t * 4 + 1] = c1;
    bufB[t * 4 + 2] = c2; bufB[t * 4 + 3] = c3;
    __syncthreads();

    // layer o: out4 @ Wo + bo, then log_softmax over 4 classes
    const int d = t >> 6;
    const int lane = t & 63;
    float p0 = 0.f, p1 = 0.f, p2 = 0.f, p3 = 0.f;
    for (int k = lane; k < 256; k += 64) {
        const float wv = Wo[k * 4 + d];
        const float4 av = *(const float4*)&bufB[k * 4];
        p0 = fmaf(av.x, wv, p0); p1 = fmaf(av.y, wv, p1);
        p2 = fmaf(av.z, wv, p2); p3 = fmaf(av.w, wv, p3);
    }
#pragma unroll
    for (int off = 32; off > 0; off >>= 1) {
        p0 += __shfl_down(p0, off); p1 += __shfl_down(p1, off);
        p2 += __shfl_down(p2, off); p3 += __shfl_down(p3, off);
    }
    if (lane == 0) {
        s5[0][d] = p0 + bo[d]; s5[1][d] = p1 + bo[d];
        s5[2][d] = p2 + bo[d]; s5[3][d] = p3 + bo[d];
    }
    __syncthreads();
    if (t < 4) {
        const float v0 = s5[t][0], v1 = s5[t][1], v2 = s5[t][2], v3 = s5[t][3];
        const float m = fmaxf(fmaxf(v0, v1), fmaxf(v2, v3));
        const float s = expf(v0 - m) + expf(v1 - m) + expf(v2 - m) + expf(v3 - m);
        const float lse = m + logf(s);
        float* op = out + (size_t)(b * Nq + n0 + t) * Dq;
        op[0] = v0 - lse; op[1] = v1 - lse; op[2] = v2 - lse; op[3] = v3 - lse;
    }
}

extern "C" void kernel_launch(void* const* d_in, const int* in_sizes, int n_in,
                              void* d_out, int out_size, void* d_ws, size_t ws_size,
                              hipStream_t stream) {
    const float* x   = (const float*)d_in[0];
    const float* adj = (const float*)d_in[1];
    const float* We1 = (const float*)d_in[2];
    const float* be1 = (const float*)d_in[3];
    const float* We2 = (const float*)d_in[4];
    const float* be2 = (const float*)d_in[5];
    const float* Wn1 = (const float*)d_in[6];
    const float* bn1 = (const float*)d_in[7];
    const float* Wn2 = (const float*)d_in[8];
    const float* bn2 = (const float*)d_in[9];
    const float* Wo1 = (const float*)d_in[10];
    const float* bo1 = (const float*)d_in[11];
    const float* Wo  = (const float*)d_in[12];
    const float* bo  = (const float*)d_in[13];
    float* out = (float*)d_out;

    // ws layout: U fp16 (1 MB) | V fp16 (1 MB) | agg f32 (2 MB)
    __half* U = (__half*)d_ws;
    __half* V = U + (size_t)Bq * Nq * Hq;
    float* aggws = (float*)((char*)d_ws + (size_t)2 * Bq * Nq * Hq * sizeof(__half));

    prep_uv<<<Bq * Nq, 256, 0, stream>>>(x, We1, be1, U, V);
    edge_gemm<<<512, 256, 0, stream>>>(U, V, We2, be2, adj, aggws);
    tail_kernel<<<512, 256, 0, stream>>>(aggws, x, Wn1, bn1, Wn2, bn2, Wo1, bo1, Wo, bo, out);
}

// Round 6
// 505.150 us; speedup vs baseline: 1.0918x; 1.0918x over previous
//
#include <hip/hip_runtime.h>
#include <hip/hip_fp16.h>
#include <math.h>

#define Bq 4
#define Nq 512
#define Dq 4
#define Hq 256

typedef _Float16 f16x8 __attribute__((ext_vector_type(8)));
typedef float f32x4 __attribute__((ext_vector_type(4)));

// packed fp16 add + relu on 8 halves (v_pk_add_f16 + v_pk_max_f16)
__device__ __forceinline__ f16x8 hadd_relu(f16x8 u, f16x8 v) {
    f16x8 s = u + v;
    const f16x8 z = (f16x8)(_Float16)0.0f;
    return __builtin_elementwise_max(s, z);
}

// ---------------- kernel 1: U/V precompute (separable first edge layer) ----
__global__ __launch_bounds__(256) void prep_uv(
    const float* __restrict__ x, const float* __restrict__ We1,
    const float* __restrict__ be1, __half* __restrict__ U, __half* __restrict__ V) {
    const int bn = blockIdx.x;   // 0..B*N-1
    const int k = threadIdx.x;   // 0..255
    const float* xp = x + bn * Dq;
    const float x0 = xp[0], x1 = xp[1], x2 = xp[2], x3 = xp[3];
    float u = be1[k];
    u = fmaf(x0, We1[0 * 256 + k], u);
    u = fmaf(x1, We1[1 * 256 + k], u);
    u = fmaf(x2, We1[2 * 256 + k], u);
    u = fmaf(x3, We1[3 * 256 + k], u);
    float v = x0 * We1[4 * 256 + k];
    v = fmaf(x1, We1[5 * 256 + k], v);
    v = fmaf(x2, We1[6 * 256 + k], v);
    v = fmaf(x3, We1[7 * 256 + k], v);
    U[(size_t)bn * Hq + k] = __float2half(u);
    V[(size_t)bn * Hq + k] = __float2half(v);
}

// ---------------- kernel 2: fused edge GEMM + adjacency aggregation --------
// agg[b,j,h] = sum_i adj[b,i,j] * relu( relu(U[b,j,:]+V[b,i,:]) @ We2[:,h] + be2[h] )
// grid 512 = b(4) x jtile(32, 16 j each) x hquarter(4, 64 h each)
// R5 post-mortem: inner-loop direct-global V reads thrashed HBM (FETCH 558MB).
// R6: LDS staging with REGISTER double-buffer prefetch — one barrier/iter,
// global V/adj latency hidden under a full compute phase.
// U fragment in 32 VGPRs (global, once); half of B (nt=0,1) in 64 VGPRs;
// nt=2,3 B from LDS Wt. In-loop LDS reads: 6 b128/ks/wave.
__global__ __launch_bounds__(256, 2) void edge_gemm(
    const __half* __restrict__ U, const __half* __restrict__ V,
    const float* __restrict__ We2, const float* __restrict__ be2,
    const float* __restrict__ adj, float* __restrict__ aggws) {
    // smem: Wt 32KB | Vs dbuf 2x8KB | adjs dbuf 2x1KB = 51200 B
    // red 16KB aliases the Vs dbuf after the main loop.
    __shared__ __align__(16) char smem[51200];
    __half* Wt = (__half*)smem;
    __half* Vs = (__half*)(smem + 32768);      // [2][16][256] halves
    float* adjs = (float*)(smem + 49152);      // [2][16][16]
    float* red = (float*)(smem + 32768);       // aliases Vs, post-loop only

    const int bid = blockIdx.x;
    const int hq_ = bid & 3;
    const int jt = (bid >> 2) & 31;
    const int b = bid >> 7;
    const int h_base = hq_ * 64;
    const int j_base = jt * 16;
    const int t = threadIdx.x;
    const int lane = t & 63;
    const int w = t >> 6;       // wave 0..3
    const int q = lane >> 4;    // quad 0..3
    const int l15 = lane & 15;

    const __half* Vb = V + (size_t)b * Nq * Hq;
    const float* adjb = adj + (size_t)b * Nq * Nq;

    // staging thread-mapping (same swizzle as reads: chunk ^ row)
    const int srow = t >> 4;            // i_local 0..15
    const int sc0 = (t & 15) * 2;       // first of 2 16B chunks

    // ---- stage Wt (once): transpose + fp16-convert We2 quarter ----
    {
        const int n = t & 63;
        const int swz = n & 31;
        for (int kk = (t >> 6); kk < 256; kk += 4) {
            float val = We2[kk * 256 + h_base + n];
            Wt[n * 256 + ((((kk >> 3) ^ swz)) << 3) + (kk & 7)] = __float2half(val);
        }
    }

    // ---- hoist U fragment (ch-invariant) straight from global ----
    f16x8 uvec[8];
#pragma unroll
    for (int ks = 0; ks < 8; ++ks) {
        const int c = ks * 4 + q;
        uvec[ks] = *(const f16x8*)&U[(size_t)(b * Nq + j_base + l15) * Hq + c * 8];
    }

    float bias[4];
#pragma unroll
    for (int nt = 0; nt < 4; ++nt) bias[nt] = be2[h_base + nt * 16 + l15];

    f32x4 agg[4];
#pragma unroll
    for (int nt = 0; nt < 4; ++nt) agg[nt] = (f32x4){0.f, 0.f, 0.f, 0.f};

    __syncthreads();  // Wt ready

    // ---- preload HALF of B (nt=0,1) into registers (ch-invariant) ----
    f16x8 bfragR[2][8];
#pragma unroll
    for (int nt = 0; nt < 2; ++nt) {
        const int rn = nt * 16 + l15;
#pragma unroll
        for (int ks = 0; ks < 8; ++ks) {
            const int c = ks * 4 + q;
            bfragR[nt][ks] = *(const f16x8*)&Wt[rn * 256 + ((c ^ (rn & 31)) << 3)];
        }
    }
    const int rn2 = 2 * 16 + l15;
    const int rn3 = 3 * 16 + l15;

    // ---- double-buffer bootstrap: buf0 = ch0; prefetch regs = ch1 ----
    uint4 pva, pvb; float pad_;
    {
        const uint4* gp = (const uint4*)(Vb + (size_t)(0 + srow) * Hq);
        pva = gp[sc0]; pvb = gp[sc0 + 1];
        pad_ = adjb[(size_t)(0 + srow) * Nq + j_base + (t & 15)];
        *(uint4*)&Vs[0 * 4096 + srow * 256 + ((sc0 ^ srow) << 3)] = pva;
        *(uint4*)&Vs[0 * 4096 + srow * 256 + (((sc0 + 1) ^ srow) << 3)] = pvb;
        adjs[0 * 256 + t] = pad_;
    }
    {
        const uint4* gp = (const uint4*)(Vb + (size_t)(16 + srow) * Hq);
        pva = gp[sc0]; pvb = gp[sc0 + 1];
        pad_ = adjb[(size_t)(16 + srow) * Nq + j_base + (t & 15)];
    }
    __syncthreads();  // buf0 visible

    for (int ch = 0; ch < 32; ++ch) {
        const int cur = ch & 1;
        const __half* Vcur = Vs + cur * 4096;
        const float* Acur = adjs + cur * 256;

        // acc init to be2 bias (bias applied pre-relu)
        f32x4 acc[4][4];
#pragma unroll
        for (int mi = 0; mi < 4; ++mi)
#pragma unroll
            for (int nt = 0; nt < 4; ++nt)
                acc[mi][nt] = (f32x4){bias[nt], bias[nt], bias[nt], bias[nt]};

#pragma unroll
        for (int ks = 0; ks < 8; ++ks) {
            const int c = ks * 4 + q;
            f16x8 afrag[4];
#pragma unroll
            for (int mi = 0; mi < 4; ++mi) {
                const int iv = w * 4 + mi;
                const f16x8 vvec = *(const f16x8*)&Vcur[iv * 256 + ((c ^ iv) << 3)];
                afrag[mi] = hadd_relu(uvec[ks], vvec);
            }
            const f16x8 b2 = *(const f16x8*)&Wt[rn2 * 256 + ((c ^ (rn2 & 31)) << 3)];
            const f16x8 b3 = *(const f16x8*)&Wt[rn3 * 256 + ((c ^ (rn3 & 31)) << 3)];
#pragma unroll
            for (int mi = 0; mi < 4; ++mi) {
                acc[mi][0] = __builtin_amdgcn_mfma_f32_16x16x32_f16(
                    afrag[mi], bfragR[0][ks], acc[mi][0], 0, 0, 0);
                acc[mi][1] = __builtin_amdgcn_mfma_f32_16x16x32_f16(
                    afrag[mi], bfragR[1][ks], acc[mi][1], 0, 0, 0);
                acc[mi][2] = __builtin_amdgcn_mfma_f32_16x16x32_f16(
                    afrag[mi], b2, acc[mi][2], 0, 0, 0);
                acc[mi][3] = __builtin_amdgcn_mfma_f32_16x16x32_f16(
                    afrag[mi], b3, acc[mi][3], 0, 0, 0);
            }
        }

        // epilogue: agg[j,h] += adj[i,j] * relu(z)   (C/D row = q*4+r -> j_local)
#pragma unroll
        for (int mi = 0; mi < 4; ++mi) {
            const int iv = w * 4 + mi;
            const f32x4 av = *(const f32x4*)&Acur[iv * 16 + q * 4];
#pragma unroll
            for (int nt = 0; nt < 4; ++nt) {
                agg[nt][0] = fmaf(av[0], fmaxf(acc[mi][nt][0], 0.f), agg[nt][0]);
                agg[nt][1] = fmaf(av[1], fmaxf(acc[mi][nt][1], 0.f), agg[nt][1]);
                agg[nt][2] = fmaf(av[2], fmaxf(acc[mi][nt][2], 0.f), agg[nt][2]);
                agg[nt][3] = fmaf(av[3], fmaxf(acc[mi][nt][3], 0.f), agg[nt][3]);
            }
        }

        // write prefetched ch+1 into alternate buffer; issue loads for ch+2
        if (ch < 31) {
            const int nxt = cur ^ 1;
            *(uint4*)&Vs[nxt * 4096 + srow * 256 + ((sc0 ^ srow) << 3)] = pva;
            *(uint4*)&Vs[nxt * 4096 + srow * 256 + (((sc0 + 1) ^ srow) << 3)] = pvb;
            adjs[nxt * 256 + t] = pad_;
            if (ch < 30) {
                const int i_base = (ch + 2) * 16;
                const uint4* gp = (const uint4*)(Vb + (size_t)(i_base + srow) * Hq);
                pva = gp[sc0]; pvb = gp[sc0 + 1];
                pad_ = adjb[(size_t)(i_base + srow) * Nq + j_base + (t & 15)];
            }
        }
        __syncthreads();
    }

    // ---- cross-wave i-reduction in LDS (red aliases Vs dbuf), plain store --
#pragma unroll
    for (int nt = 0; nt < 4; ++nt)
#pragma unroll
        for (int r = 0; r < 4; ++r)
            red[w * 1024 + (q * 4 + r) * 64 + nt * 16 + l15] = agg[nt][r];
    __syncthreads();
    {
        const int j = t >> 4;
        const int h0 = (t & 15) * 4;
        f32x4 s = *(const f32x4*)&red[0 * 1024 + j * 64 + h0];
        s += *(const f32x4*)&red[1 * 1024 + j * 64 + h0];
        s += *(const f32x4*)&red[2 * 1024 + j * 64 + h0];
        s += *(const f32x4*)&red[3 * 1024 + j * 64 + h0];
        *(f32x4*)&aggws[(size_t)(b * Nq + j_base + j) * Hq + h_base + h0] = s;
    }
}

// ---------------- kernel 3: node MLP tail + log_softmax -------------------
__global__ __launch_bounds__(256) void tail_kernel(
    const float* __restrict__ aggws, const float* __restrict__ x,
    const float* __restrict__ Wn1, const float* __restrict__ bn1,
    const float* __restrict__ Wn2, const float* __restrict__ bn2,
    const float* __restrict__ Wo1, const float* __restrict__ bo1,
    const float* __restrict__ Wo, const float* __restrict__ bo,
    float* __restrict__ out) {
    __shared__ __align__(16) float bufA[256 * 4];
    __shared__ __align__(16) float bufB[256 * 4];
    __shared__ float xs[4][4];
    __shared__ float s5[4][4];
    const int bid = blockIdx.x;
    const int b = bid >> 7;
    const int n0 = (bid & 127) * 4;
    const int t = threadIdx.x;

#pragma unroll
    for (int ni = 0; ni < 4; ++ni)
        bufA[t * 4 + ni] = aggws[(size_t)(b * Nq + n0 + ni) * Hq + t];
    if (t < 16) xs[t >> 2][t & 3] = x[(size_t)(b * Nq + n0 + (t >> 2)) * Dq + (t & 3)];
    __syncthreads();

    float c0, c1, c2, c3;
    // layer n1: relu(agg @ Wn1 + bn1)
    c0 = c1 = c2 = c3 = bn1[t];
#pragma unroll 8
    for (int k = 0; k < 256; ++k) {
        const float wv = Wn1[k * 256 + t];
        const float4 av = *(const float4*)&bufA[k * 4];
        c0 = fmaf(av.x, wv, c0); c1 = fmaf(av.y, wv, c1);
        c2 = fmaf(av.z, wv, c2); c3 = fmaf(av.w, wv, c3);
    }
    bufB[t * 4 + 0] = fmaxf(c0, 0.f); bufB[t * 4 + 1] = fmaxf(c1, 0.f);
    bufB[t * 4 + 2] = fmaxf(c2, 0.f); bufB[t * 4 + 3] = fmaxf(c3, 0.f);
    __syncthreads();

    // layer n2: relu(out1 @ Wn2 + bn2)
    c0 = c1 = c2 = c3 = bn2[t];
#pragma unroll 8
    for (int k = 0; k < 256; ++k) {
        const float wv = Wn2[k * 256 + t];
        const float4 av = *(const float4*)&bufB[k * 4];
        c0 = fmaf(av.x, wv, c0); c1 = fmaf(av.y, wv, c1);
        c2 = fmaf(av.z, wv, c2); c3 = fmaf(av.w, wv, c3);
    }
    bufA[t * 4 + 0] = fmaxf(c0, 0.f); bufA[t * 4 + 1] = fmaxf(c1, 0.f);
    bufA[t * 4 + 2] = fmaxf(c2, 0.f); bufA[t * 4 + 3] = fmaxf(c3, 0.f);
    __syncthreads();

    // layer o1: concat(x, out2) @ Wo1 + bo1   (no relu)
    c0 = c1 = c2 = c3 = bo1[t];
#pragma unroll
    for (int d = 0; d < 4; ++d) {
        const float wv = Wo1[d * 256 + t];
        c0 = fmaf(xs[0][d], wv, c0); c1 = fmaf(xs[1][d], wv, c1);
        c2 = fmaf(xs[2][d], wv, c2); c3 = fmaf(xs[3][d], wv, c3);
    }
#pragma unroll 8
    for (int k = 0; k < 256; ++k) {
        const float wv = Wo1[(4 + k) * 256 + t];
        const float4 av = *(const float4*)&bufA[k * 4];
        c0 = fmaf(av.x, wv, c0); c1 = fmaf(av.y, wv, c1);
        c2 = fmaf(av.z, wv, c2); c3 = fmaf(av.w, wv, c3);
    }
    bufB[t * 4 + 0] = c0; bufB[t * 4 + 1] = c1;
    bufB[t * 4 + 2] = c2; bufB[t * 4 + 3] = c3;
    __syncthreads();

    // layer o: out4 @ Wo + bo, then log_softmax over 4 classes
    const int d = t >> 6;
    const int lane = t & 63;
    float p0 = 0.f, p1 = 0.f, p2 = 0.f, p3 = 0.f;
    for (int k = lane; k < 256; k += 64) {
        const float wv = Wo[k * 4 + d];
        const float4 av = *(const float4*)&bufB[k * 4];
        p0 = fmaf(av.x, wv, p0); p1 = fmaf(av.y, wv, p1);
        p2 = fmaf(av.z, wv, p2); p3 = fmaf(av.w, wv, p3);
    }
#pragma unroll
    for (int off = 32; off > 0; off >>= 1) {
        p0 += __shfl_down(p0, off); p1 += __shfl_down(p1, off);
        p2 += __shfl_down(p2, off); p3 += __shfl_down(p3, off);
    }
    if (lane == 0) {
        s5[0][d] = p0 + bo[d]; s5[1][d] = p1 + bo[d];
        s5[2][d] = p2 + bo[d]; s5[3][d] = p3 + bo[d];
    }
    __syncthreads();
    if (t < 4) {
        const float v0 = s5[t][0], v1 = s5[t][1], v2 = s5[t][2], v3 = s5[t][3];
        const float m = fmaxf(fmaxf(v0, v1), fmaxf(v2, v3));
        const float s = expf(v0 - m) + expf(v1 - m) + expf(v2 - m) + expf(v3 - m);
        const float lse = m + logf(s);
        float* op = out + (size_t)(b * Nq + n0 + t) * Dq;
        op[0] = v0 - lse; op[1] = v1 - lse; op[2] = v2 - lse; op[3] = v3 - lse;
    }
}

extern "C" void kernel_launch(void* const* d_in, const int* in_sizes, int n_in,
                              void* d_out, int out_size, void* d_ws, size_t ws_size,
                              hipStream_t stream) {
    const float* x   = (const float*)d_in[0];
    const float* adj = (const float*)d_in[1];
    const float* We1 = (const float*)d_in[2];
    const float* be1 = (const float*)d_in[3];
    const float* We2 = (const float*)d_in[4];
    const float* be2 = (const float*)d_in[5];
    const float* Wn1 = (const float*)d_in[6];
    const float* bn1 = (const float*)d_in[7];
    const float* Wn2 = (const float*)d_in[8];
    const float* bn2 = (const float*)d_in[9];
    const float* Wo1 = (const float*)d_in[10];
    const float* bo1 = (const float*)d_in[11];
    const float* Wo  = (const float*)d_in[12];
    const float* bo  = (const float*)d_in[13];
    float* out = (float*)d_out;

    // ws layout: U fp16 (1 MB) | V fp16 (1 MB) | agg f32 (2 MB)
    __half* U = (__half*)d_ws;
    __half* V = U + (size_t)Bq * Nq * Hq;
    float* aggws = (float*)((char*)d_ws + (size_t)2 * Bq * Nq * Hq * sizeof(__half));

    prep_uv<<<Bq * Nq, 256, 0, stream>>>(x, We1, be1, U, V);
    edge_gemm<<<512, 256, 0, stream>>>(U, V, We2, be2, adj, aggws);
    tail_kernel<<<512, 256, 0, stream>>>(aggws, x, Wn1, bn1, Wn2, bn2, Wo1, bo1, Wo, bo, out);
}

// Round 7
// 242.927 us; speedup vs baseline: 2.2703x; 2.0794x over previous
//
#include <hip/hip_runtime.h>
#include <hip/hip_fp16.h>
#include <math.h>

#define Bq 4
#define Nq 512
#define Dq 4
#define Hq 256

typedef _Float16 f16x8 __attribute__((ext_vector_type(8)));
typedef float f32x4 __attribute__((ext_vector_type(4)));

// packed fp16 add + relu on 8 halves (v_pk_add_f16 + v_pk_max_f16)
__device__ __forceinline__ f16x8 hadd_relu(f16x8 u, f16x8 v) {
    f16x8 s = u + v;
    const f16x8 z = (f16x8)(_Float16)0.0f;
    return __builtin_elementwise_max(s, z);
}

// ---------------- kernel 1: U/V precompute (separable first edge layer) ----
__global__ __launch_bounds__(256) void prep_uv(
    const float* __restrict__ x, const float* __restrict__ We1,
    const float* __restrict__ be1, __half* __restrict__ U, __half* __restrict__ V) {
    const int bn = blockIdx.x;   // 0..B*N-1
    const int k = threadIdx.x;   // 0..255
    const float* xp = x + bn * Dq;
    const float x0 = xp[0], x1 = xp[1], x2 = xp[2], x3 = xp[3];
    float u = be1[k];
    u = fmaf(x0, We1[0 * 256 + k], u);
    u = fmaf(x1, We1[1 * 256 + k], u);
    u = fmaf(x2, We1[2 * 256 + k], u);
    u = fmaf(x3, We1[3 * 256 + k], u);
    float v = x0 * We1[4 * 256 + k];
    v = fmaf(x1, We1[5 * 256 + k], v);
    v = fmaf(x2, We1[6 * 256 + k], v);
    v = fmaf(x3, We1[7 * 256 + k], v);
    U[(size_t)bn * Hq + k] = __float2half(u);
    V[(size_t)bn * Hq + k] = __float2half(v);
}

// ---------------- kernel 2: fused edge GEMM + adjacency aggregation --------
// agg[b,j,h] = sum_i adj[b,i,j] * relu( relu(U[b,j,:]+V[b,i,:]) @ We2[:,h] + be2[h] )
// grid 512 = b(4) x jtile(32, 16 j each) x hquarter(4, 64 h each)
// R7 = R2's exact read pattern/register footprint (124 VGPR, no hoists) +
// double-buffered Vs/adjs staging with REGISTER prefetch issued 2 iterations
// ahead and ONE barrier per iteration (R2 had 2 + exposed vmcnt(0) waits).
// R3/R6 lesson: any >~10-reg hoist on top of the 64-AGPR acc spills.
__global__ __launch_bounds__(256, 2) void edge_gemm(
    const __half* __restrict__ U, const __half* __restrict__ V,
    const float* __restrict__ We2, const float* __restrict__ be2,
    const float* __restrict__ adj, float* __restrict__ aggws) {
    // smem: Wt 32K | Us 8K | Vs dbuf 2x8K | adjs dbuf 2x1K = 59392 B
    // red 16KB aliases the Vs dbuf after the main loop.
    __shared__ __align__(16) char smem[59392];
    __half* Wt = (__half*)smem;
    __half* Us = (__half*)(smem + 32768);
    __half* Vs = (__half*)(smem + 40960);      // [2][16][256] halves
    float* adjs = (float*)(smem + 57344);      // [2][16][16]
    float* red = (float*)(smem + 40960);       // aliases Vs, post-loop only

    const int bid = blockIdx.x;
    const int hq_ = bid & 3;
    const int jt = (bid >> 2) & 31;
    const int b = bid >> 7;
    const int h_base = hq_ * 64;
    const int j_base = jt * 16;
    const int t = threadIdx.x;
    const int lane = t & 63;
    const int w = t >> 6;       // wave 0..3
    const int q = lane >> 4;    // quad 0..3
    const int l15 = lane & 15;

    const __half* Vb = V + (size_t)b * Nq * Hq;
    const float* adjb = adj + (size_t)b * Nq * Nq;

    // staging thread-mapping (same swizzle as reads: chunk ^ row)
    const int srow = t >> 4;            // row 0..15
    const int sc0 = (t & 15) * 2;       // first of 2 16B chunks

    // ---- stage Wt (once): transpose + fp16-convert We2 quarter ----
    {
        const int n = t & 63;
        const int swz = n & 31;
        for (int kk = (t >> 6); kk < 256; kk += 4) {
            float val = We2[kk * 256 + h_base + n];
            Wt[n * 256 + ((((kk >> 3) ^ swz)) << 3) + (kk & 7)] = __float2half(val);
        }
    }
    // ---- stage Us (once): 16 j rows ----
    {
        const uint4* gp = (const uint4*)(U + (size_t)(b * Nq + j_base + srow) * Hq);
        uint4 v0 = gp[sc0];
        uint4 v1 = gp[sc0 + 1];
        *(uint4*)&Us[srow * 256 + ((sc0 ^ srow) << 3)] = v0;
        *(uint4*)&Us[srow * 256 + (((sc0 + 1) ^ srow) << 3)] = v1;
    }

    float bias[4];
#pragma unroll
    for (int nt = 0; nt < 4; ++nt) bias[nt] = be2[h_base + nt * 16 + l15];

    f32x4 agg[4];
#pragma unroll
    for (int nt = 0; nt < 4; ++nt) agg[nt] = (f32x4){0.f, 0.f, 0.f, 0.f};

    // ---- double-buffer bootstrap: buf0 = ch0; prefetch regs = ch1 ----
    uint4 pva, pvb; float pad_;
    {
        const uint4* gp = (const uint4*)(Vb + (size_t)(0 + srow) * Hq);
        pva = gp[sc0]; pvb = gp[sc0 + 1];
        pad_ = adjb[(size_t)(0 + srow) * Nq + j_base + (t & 15)];
        *(uint4*)&Vs[0 * 4096 + srow * 256 + ((sc0 ^ srow) << 3)] = pva;
        *(uint4*)&Vs[0 * 4096 + srow * 256 + (((sc0 + 1) ^ srow) << 3)] = pvb;
        adjs[0 * 256 + t] = pad_;
    }
    {
        const uint4* gp = (const uint4*)(Vb + (size_t)(16 + srow) * Hq);
        pva = gp[sc0]; pvb = gp[sc0 + 1];
        pad_ = adjb[(size_t)(16 + srow) * Nq + j_base + (t & 15)];
    }
    __syncthreads();  // Wt/Us/buf0 visible

    for (int ch = 0; ch < 32; ++ch) {
        const int cur = ch & 1;
        const __half* Vcur = Vs + cur * 4096;
        const float* Acur = adjs + cur * 256;

        // acc init to be2 bias (bias applied pre-relu)
        f32x4 acc[4][4];
#pragma unroll
        for (int mi = 0; mi < 4; ++mi)
#pragma unroll
            for (int nt = 0; nt < 4; ++nt)
                acc[mi][nt] = (f32x4){bias[nt], bias[nt], bias[nt], bias[nt]};

#pragma unroll
        for (int ks = 0; ks < 8; ++ks) {
            const int c = ks * 4 + q;  // 16B chunk index along k
            // A fragments: row m=l15 (j_local), k = ks*32 + q*8 + jj
            const f16x8 uvec = *(const f16x8*)&Us[l15 * 256 + ((c ^ l15) << 3)];
            f16x8 afrag[4];
#pragma unroll
            for (int mi = 0; mi < 4; ++mi) {
                const int iv = w * 4 + mi;  // i_local for this wave/m-tile
                const f16x8 vvec = *(const f16x8*)&Vcur[iv * 256 + ((c ^ iv) << 3)];
                afrag[mi] = hadd_relu(uvec, vvec);
            }
            // B fragments: n = nt*16+l15
            f16x8 bf[4];
#pragma unroll
            for (int nt = 0; nt < 4; ++nt) {
                const int rn = nt * 16 + l15;
                bf[nt] = *(const f16x8*)&Wt[rn * 256 + ((c ^ (rn & 31)) << 3)];
            }
#pragma unroll
            for (int mi = 0; mi < 4; ++mi)
#pragma unroll
                for (int nt = 0; nt < 4; ++nt)
                    acc[mi][nt] = __builtin_amdgcn_mfma_f32_16x16x32_f16(
                        afrag[mi], bf[nt], acc[mi][nt], 0, 0, 0);
        }

        // epilogue: agg[j,h] += adj[i,j] * relu(z)   (C/D row = q*4+r -> j_local)
#pragma unroll
        for (int mi = 0; mi < 4; ++mi) {
            const int iv = w * 4 + mi;
            const f32x4 av = *(const f32x4*)&Acur[iv * 16 + q * 4];
#pragma unroll
            for (int nt = 0; nt < 4; ++nt) {
                agg[nt][0] = fmaf(av[0], fmaxf(acc[mi][nt][0], 0.f), agg[nt][0]);
                agg[nt][1] = fmaf(av[1], fmaxf(acc[mi][nt][1], 0.f), agg[nt][1]);
                agg[nt][2] = fmaf(av[2], fmaxf(acc[mi][nt][2], 0.f), agg[nt][2]);
                agg[nt][3] = fmaf(av[3], fmaxf(acc[mi][nt][3], 0.f), agg[nt][3]);
            }
        }

        // write prefetched ch+1 into alternate buffer; issue loads for ch+2.
        // Safe: nxt holds ch-1 data nobody reads (all waves passed the
        // end-of-(ch-1) barrier); data for these writes was loaded a full
        // compute phase ago, so the vmcnt wait is ~instant.
        if (ch < 31) {
            const int nxt = cur ^ 1;
            *(uint4*)&Vs[nxt * 4096 + srow * 256 + ((sc0 ^ srow) << 3)] = pva;
            *(uint4*)&Vs[nxt * 4096 + srow * 256 + (((sc0 + 1) ^ srow) << 3)] = pvb;
            adjs[nxt * 256 + t] = pad_;
            if (ch < 30) {
                const int i_base = (ch + 2) * 16;
                const uint4* gp = (const uint4*)(Vb + (size_t)(i_base + srow) * Hq);
                pva = gp[sc0]; pvb = gp[sc0 + 1];
                pad_ = adjb[(size_t)(i_base + srow) * Nq + j_base + (t & 15)];
            }
        }
        __syncthreads();  // one barrier per iteration
    }

    // ---- cross-wave i-reduction in LDS (red aliases Vs dbuf), plain store --
#pragma unroll
    for (int nt = 0; nt < 4; ++nt)
#pragma unroll
        for (int r = 0; r < 4; ++r)
            red[w * 1024 + (q * 4 + r) * 64 + nt * 16 + l15] = agg[nt][r];
    __syncthreads();
    {
        const int j = t >> 4;
        const int h0 = (t & 15) * 4;
        f32x4 s = *(const f32x4*)&red[0 * 1024 + j * 64 + h0];
        s += *(const f32x4*)&red[1 * 1024 + j * 64 + h0];
        s += *(const f32x4*)&red[2 * 1024 + j * 64 + h0];
        s += *(const f32x4*)&red[3 * 1024 + j * 64 + h0];
        *(f32x4*)&aggws[(size_t)(b * Nq + j_base + j) * Hq + h_base + h0] = s;
    }
}

// ---------------- kernel 3: node MLP tail + log_softmax -------------------
__global__ __launch_bounds__(256) void tail_kernel(
    const float* __restrict__ aggws, const float* __restrict__ x,
    const float* __restrict__ Wn1, const float* __restrict__ bn1,
    const float* __restrict__ Wn2, const float* __restrict__ bn2,
    const float* __restrict__ Wo1, const float* __restrict__ bo1,
    const float* __restrict__ Wo, const float* __restrict__ bo,
    float* __restrict__ out) {
    __shared__ __align__(16) float bufA[256 * 4];
    __shared__ __align__(16) float bufB[256 * 4];
    __shared__ float xs[4][4];
    __shared__ float s5[4][4];
    const int bid = blockIdx.x;
    const int b = bid >> 7;
    const int n0 = (bid & 127) * 4;
    const int t = threadIdx.x;

#pragma unroll
    for (int ni = 0; ni < 4; ++ni)
        bufA[t * 4 + ni] = aggws[(size_t)(b * Nq + n0 + ni) * Hq + t];
    if (t < 16) xs[t >> 2][t & 3] = x[(size_t)(b * Nq + n0 + (t >> 2)) * Dq + (t & 3)];
    __syncthreads();

    float c0, c1, c2, c3;
    // layer n1: relu(agg @ Wn1 + bn1)
    c0 = c1 = c2 = c3 = bn1[t];
#pragma unroll 8
    for (int k = 0; k < 256; ++k) {
        const float wv = Wn1[k * 256 + t];
        const float4 av = *(const float4*)&bufA[k * 4];
        c0 = fmaf(av.x, wv, c0); c1 = fmaf(av.y, wv, c1);
        c2 = fmaf(av.z, wv, c2); c3 = fmaf(av.w, wv, c3);
    }
    bufB[t * 4 + 0] = fmaxf(c0, 0.f); bufB[t * 4 + 1] = fmaxf(c1, 0.f);
    bufB[t * 4 + 2] = fmaxf(c2, 0.f); bufB[t * 4 + 3] = fmaxf(c3, 0.f);
    __syncthreads();

    // layer n2: relu(out1 @ Wn2 + bn2)
    c0 = c1 = c2 = c3 = bn2[t];
#pragma unroll 8
    for (int k = 0; k < 256; ++k) {
        const float wv = Wn2[k * 256 + t];
        const float4 av = *(const float4*)&bufB[k * 4];
        c0 = fmaf(av.x, wv, c0); c1 = fmaf(av.y, wv, c1);
        c2 = fmaf(av.z, wv, c2); c3 = fmaf(av.w, wv, c3);
    }
    bufA[t * 4 + 0] = fmaxf(c0, 0.f); bufA[t * 4 + 1] = fmaxf(c1, 0.f);
    bufA[t * 4 + 2] = fmaxf(c2, 0.f); bufA[t * 4 + 3] = fmaxf(c3, 0.f);
    __syncthreads();

    // layer o1: concat(x, out2) @ Wo1 + bo1   (no relu)
    c0 = c1 = c2 = c3 = bo1[t];
#pragma unroll
    for (int d = 0; d < 4; ++d) {
        const float wv = Wo1[d * 256 + t];
        c0 = fmaf(xs[0][d], wv, c0); c1 = fmaf(xs[1][d], wv, c1);
        c2 = fmaf(xs[2][d], wv, c2); c3 = fmaf(xs[3][d], wv, c3);
    }
#pragma unroll 8
    for (int k = 0; k < 256; ++k) {
        const float wv = Wo1[(4 + k) * 256 + t];
        const float4 av = *(const float4*)&bufA[k * 4];
        c0 = fmaf(av.x, wv, c0); c1 = fmaf(av.y, wv, c1);
        c2 = fmaf(av.z, wv, c2); c3 = fmaf(av.w, wv, c3);
    }
    bufB[t * 4 + 0] = c0; bufB[t * 4 + 1] = c1;
    bufB[t * 4 + 2] = c2; bufB[t * 4 + 3] = c3;
    __syncthreads();

    // layer o: out4 @ Wo + bo, then log_softmax over 4 classes
    const int d = t >> 6;
    const int lane = t & 63;
    float p0 = 0.f, p1 = 0.f, p2 = 0.f, p3 = 0.f;
    for (int k = lane; k < 256; k += 64) {
        const float wv = Wo[k * 4 + d];
        const float4 av = *(const float4*)&bufB[k * 4];
        p0 = fmaf(av.x, wv, p0); p1 = fmaf(av.y, wv, p1);
        p2 = fmaf(av.z, wv, p2); p3 = fmaf(av.w, wv, p3);
    }
#pragma unroll
    for (int off = 32; off > 0; off >>= 1) {
        p0 += __shfl_down(p0, off); p1 += __shfl_down(p1, off);
        p2 += __shfl_down(p2, off); p3 += __shfl_down(p3, off);
    }
    if (lane == 0) {
        s5[0][d] = p0 + bo[d]; s5[1][d] = p1 + bo[d];
        s5[2][d] = p2 + bo[d]; s5[3][d] = p3 + bo[d];
    }
    __syncthreads();
    if (t < 4) {
        const float v0 = s5[t][0], v1 = s5[t][1], v2 = s5[t][2], v3 = s5[t][3];
        const float m = fmaxf(fmaxf(v0, v1), fmaxf(v2, v3));
        const float s = expf(v0 - m) + expf(v1 - m) + expf(v2 - m) + expf(v3 - m);
        const float lse = m + logf(s);
        float* op = out + (size_t)(b * Nq + n0 + t) * Dq;
        op[0] = v0 - lse; op[1] = v1 - lse; op[2] = v2 - lse; op[3] = v3 - lse;
    }
}

extern "C" void kernel_launch(void* const* d_in, const int* in_sizes, int n_in,
                              void* d_out, int out_size, void* d_ws, size_t ws_size,
                              hipStream_t stream) {
    const float* x   = (const float*)d_in[0];
    const float* adj = (const float*)d_in[1];
    const float* We1 = (const float*)d_in[2];
    const float* be1 = (const float*)d_in[3];
    const float* We2 = (const float*)d_in[4];
    const float* be2 = (const float*)d_in[5];
    const float* Wn1 = (const float*)d_in[6];
    const float* bn1 = (const float*)d_in[7];
    const float* Wn2 = (const float*)d_in[8];
    const float* bn2 = (const float*)d_in[9];
    const float* Wo1 = (const float*)d_in[10];
    const float* bo1 = (const float*)d_in[11];
    const float* Wo  = (const float*)d_in[12];
    const float* bo  = (const float*)d_in[13];
    float* out = (float*)d_out;

    // ws layout: U fp16 (1 MB) | V fp16 (1 MB) | agg f32 (2 MB)
    __half* U = (__half*)d_ws;
    __half* V = U + (size_t)Bq * Nq * Hq;
    float* aggws = (float*)((char*)d_ws + (size_t)2 * Bq * Nq * Hq * sizeof(__half));

    prep_uv<<<Bq * Nq, 256, 0, stream>>>(x, We1, be1, U, V);
    edge_gemm<<<512, 256, 0, stream>>>(U, V, We2, be2, adj, aggws);
    tail_kernel<<<512, 256, 0, stream>>>(aggws, x, Wn1, bn1, Wn2, bn2, Wo1, bo1, Wo, bo, out);
}